// Round 18
// baseline (72.790 us; speedup 1.0000x reference)
//
#include <hip/hip_runtime.h>
#include <hip/hip_bf16.h>

#define N_ROWS 16384
#define DIM 128

constexpr float INV_T = 1.0f / 0.07f;                 // 14.2857...
constexpr float LOG2E = 1.4426950408889634f;
constexpr float C1    = INV_T * LOG2E;                // 20.6099  (exp2 scale)
constexpr float SOP   = 4.5398160f;                   // sqrt(C1), split per operand
constexpr float LN2   = 0.69314718055994530942f;

typedef int   v4i    __attribute__((ext_vector_type(4)));
typedef int   v8i    __attribute__((ext_vector_type(8)));
typedef float f32x16 __attribute__((ext_vector_type(16)));

typedef const __attribute__((address_space(1))) void* gptr1_t;
typedef __attribute__((address_space(3))) void*       sptr3_t;

// p8 PRE-TILED as the B-operand of mfma_scale_f32_32x32x64_f8f6f4 (proven R14):
// one 32-col tile = 4KB contiguous: [c2][h2][b2][col32][16B]
#define TILE_BYTES 4096
#define BM 256                        /* rows per block (4 waves x 64)    */
#define WROWS 64
#define COLSPLIT 32                   /* grid 2048 = 8 blocks/CU supply:  */
                                      /* fill the 6-block VGPR cap (was 4)*/
#define COLS_PER (N_ROWS / COLSPLIT)  /* 512 */
#define NJT (COLS_PER / 32)           /* 16 tiles */

// ---------------------------------------------------------------------------
// Kernel 1: normalize; both operands scaled by sqrt(C1); fp8 e4m3 outputs
// (A row-major, P tiled); exact fp32 diagonal logit; zeroes sacc. (proven R14)
// ---------------------------------------------------------------------------
__global__ __launch_bounds__(256) void norm_kernel(
    const float* __restrict__ A, const float* __restrict__ P,
    ushort* __restrict__ a8u, ushort* __restrict__ p8u,
    float* __restrict__ diag, float* __restrict__ sacc)
{
    if (threadIdx.x < 4) sacc[blockIdx.x * 4 + threadIdx.x] = 0.f;
    int row  = blockIdx.x * 4 + (threadIdx.x >> 6);
    int lane = threadIdx.x & 63;
    float2 av = *(const float2*)(A + (size_t)row * DIM + lane * 2);
    float2 pv = *(const float2*)(P + (size_t)row * DIM + lane * 2);
    float ssa = av.x * av.x + av.y * av.y;
    float ssp = pv.x * pv.x + pv.y * pv.y;
    float dp  = av.x * pv.x + av.y * pv.y;
    #pragma unroll
    for (int m = 1; m < 64; m <<= 1) {
        ssa += __shfl_xor(ssa, m);
        ssp += __shfl_xor(ssp, m);
        dp  += __shfl_xor(dp,  m);
    }
    float ra = 1.0f / fmaxf(sqrtf(ssa), 1e-12f);
    float rp = 1.0f / fmaxf(sqrtf(ssp), 1e-12f);
    if (lane == 0) diag[row] = dp * ra * rp * INV_T;
    float sa = ra * SOP, sp = rp * SOP;
    int apk = __builtin_amdgcn_cvt_pk_fp8_f32(av.x * sa, av.y * sa, 0, false);
    int ppk = __builtin_amdgcn_cvt_pk_fp8_f32(pv.x * sp, pv.y * sp, 0, false);
    a8u[(size_t)row * 64 + lane] = (ushort)apk;
    size_t off = (size_t)(row >> 5) * 2048 + (lane >> 5) * 1024
               + ((lane >> 4) & 1) * 512 + ((lane >> 3) & 1) * 256
               + (row & 31) * 8 + (lane & 7);
    p8u[off] = (ushort)ppk;
}

// ---------------------------------------------------------------------------
// Kernel 2: per-row sum of exp2(C1*cos - C1) via MX-fp8 32x32x64 MFMA.
// R14 VERBATIM except COLSPLIT 16->32: counted vmcnt (never 0 mid-loop),
// triple-buffered 4KB tiles via global_load_lds, one s_barrier per tile,
// setprio around the MFMA cluster.
// Caps at VGPR=76: 6 waves/SIMD; LDS 12KB: 13 blocks/CU. Grid 2048 = 8
// blocks/CU supply -> residency fills to 6 blocks (24 waves/CU, was 16).
// REG-CAP DISCIPLINE: (256,2) ONLY — tighter caps spill (R2/R4/R6).
// ---------------------------------------------------------------------------
__global__ __launch_bounds__(256, 2) void lse_kernel(
    const ushort* __restrict__ a8u, const ushort* __restrict__ p8u,
    float* __restrict__ s_accum)
{
    __shared__ __attribute__((aligned(16))) char btile[3][TILE_BYTES];

    int colseg = blockIdx.x & (COLSPLIT - 1);   // bid%8 -> XCD-pinned segment
    int rowblk = blockIdx.x / COLSPLIT;
    int wave = threadIdx.x >> 6;
    int lane = threadIdx.x & 63;
    int c31  = lane & 31, hi = lane >> 5;
    int row0 = rowblk * BM + wave * WROWS;

    // A fragments: 2 row-tiles x 2 K-chunks, 32B/lane each (v8i), row-major a8
    const char* a8 = (const char*)a8u;
    v8i afA0 = *(const v8i*)(a8 + (size_t)(row0 + c31) * 128 +       hi * 32);
    v8i afA1 = *(const v8i*)(a8 + (size_t)(row0 + c31) * 128 + 64  + hi * 32);
    v8i afB0 = *(const v8i*)(a8 + (size_t)(row0 + 32 + c31) * 128 +      hi * 32);
    v8i afB1 = *(const v8i*)(a8 + (size_t)(row0 + 32 + c31) * 128 + 64 + hi * 32);

    f32x16 cinit;
    #pragma unroll
    for (int r = 0; r < 16; ++r) cinit[r] = -C1;

    float s0[16], s1[16];
    #pragma unroll
    for (int r = 0; r < 16; ++r) { s0[r] = 0.f; s1[r] = 0.f; }

    const char* seg = (const char*)p8u + (size_t)colseg * NJT * TILE_BYTES;
    char* lds = (char*)&btile[0][0];
    int choff = wave * 1024 + lane * 16;   // each wave stages 1KB of the 4KB tile

    auto STAGE = [&](int t, int buf) {
        __builtin_amdgcn_global_load_lds(
            (gptr1_t)(seg + (size_t)t * TILE_BYTES + choff),
            (sptr3_t)(lds + buf * TILE_BYTES + choff), 16, 0, 0);
    };

    int rdoff = hi * 1024 + c31 * 16;

    f32x16 acc0, acc1;

    // prologue: stage tiles 0,1 -> bufs 0,1 (one load each)
    STAGE(0, 0);
    STAGE(1, 1);

    for (int jt = 0; jt < NJT; ++jt) {
        if (jt < NJT - 1) asm volatile("s_waitcnt vmcnt(1)" ::: "memory");
        else              asm volatile("s_waitcnt vmcnt(0)" ::: "memory");
        __builtin_amdgcn_s_barrier();
        __builtin_amdgcn_sched_barrier(0);

        if (jt + 2 < NJT) STAGE(jt + 2, (jt + 2) % 3);

        const char* tb = lds + (jt % 3) * TILE_BYTES;
        v4i x0 = *(const v4i*)(tb + rdoff);
        v4i y0 = *(const v4i*)(tb + rdoff + 512);
        v4i x1 = *(const v4i*)(tb + 2048 + rdoff);
        v4i y1 = *(const v4i*)(tb + 2048 + rdoff + 512);
        v8i b0, b1;
        #pragma unroll
        for (int j = 0; j < 4; ++j) {
            b0[j] = x0[j]; b0[4 + j] = y0[j];
            b1[j] = x1[j]; b1[4 + j] = y1[j];
        }

        __builtin_amdgcn_s_setprio(1);
        acc0 = __builtin_amdgcn_mfma_scale_f32_32x32x64_f8f6f4(
            afA0, b0, cinit, 0, 0, 0, 0x7f7f7f7f, 0, 0x7f7f7f7f);
        acc1 = __builtin_amdgcn_mfma_scale_f32_32x32x64_f8f6f4(
            afB0, b0, cinit, 0, 0, 0, 0x7f7f7f7f, 0, 0x7f7f7f7f);
        acc0 = __builtin_amdgcn_mfma_scale_f32_32x32x64_f8f6f4(
            afA1, b1, acc0, 0, 0, 0, 0x7f7f7f7f, 0, 0x7f7f7f7f);
        acc1 = __builtin_amdgcn_mfma_scale_f32_32x32x64_f8f6f4(
            afB1, b1, acc1, 0, 0, 0, 0x7f7f7f7f, 0, 0x7f7f7f7f);
        __builtin_amdgcn_s_setprio(0);

        #pragma unroll
        for (int r = 0; r < 16; ++r) {
            s0[r] += __builtin_amdgcn_exp2f(acc0[r]);
            s1[r] += __builtin_amdgcn_exp2f(acc1[r]);
        }
    }

    // reduce each row's 32 column-lanes (within each 32-lane half), one atomic
    #pragma unroll
    for (int t = 0; t < 2; ++t)
        #pragma unroll
        for (int r = 0; r < 16; ++r) {
            float v = (t ? s1[r] : s0[r]);
            v += __shfl_xor(v, 1);
            v += __shfl_xor(v, 2);
            v += __shfl_xor(v, 4);
            v += __shfl_xor(v, 8);
            v += __shfl_xor(v, 16);
            if (c31 == 0)
                atomicAdd(&s_accum[row0 + t * 32 + (r & 3) + 8 * (r >> 2) + 4 * hi], v);
        }
}

// ---------------------------------------------------------------------------
// Kernel 3: loss = mean( ln(s_i) + 1/T - diag_i )
// ---------------------------------------------------------------------------
__global__ __launch_bounds__(1024) void finalize_kernel(
    const float* __restrict__ s_acc, const float* __restrict__ diag,
    float* __restrict__ out)
{
    float acc = 0.f;
    int t = threadIdx.x;
    #pragma unroll
    for (int i = 0; i < 4; ++i) {
        int idx = (i * 1024 + t) * 4;
        float4 sv = *(const float4*)(s_acc + idx);
        float4 dv = *(const float4*)(diag + idx);
        acc += __builtin_amdgcn_logf(sv.x) * LN2 + INV_T - dv.x;
        acc += __builtin_amdgcn_logf(sv.y) * LN2 + INV_T - dv.y;
        acc += __builtin_amdgcn_logf(sv.z) * LN2 + INV_T - dv.z;
        acc += __builtin_amdgcn_logf(sv.w) * LN2 + INV_T - dv.w;
    }
    #pragma unroll
    for (int m = 1; m < 64; m <<= 1) acc += __shfl_xor(acc, m);
    __shared__ float wsum[16];
    if ((t & 63) == 0) wsum[t >> 6] = acc;
    __syncthreads();
    if (t == 0) {
        float r = 0.f;
        #pragma unroll
        for (int i = 0; i < 16; ++i) r += wsum[i];
        out[0] = r / (float)N_ROWS;
    }
}

// ---------------------------------------------------------------------------
extern "C" void kernel_launch(void* const* d_in, const int* in_sizes, int n_in,
                              void* d_out, int out_size, void* d_ws, size_t ws_size,
                              hipStream_t stream)
{
    const float* A = (const float*)d_in[0];
    const float* P = (const float*)d_in[1];
    float* out = (float*)d_out;

    char* ws = (char*)d_ws;
    ushort* a8u  = (ushort*)ws;                                   // 2 MB fp8
    ushort* p8u  = (ushort*)(ws + (size_t)2 * 1024 * 1024);       // 2 MB fp8 tiled
    float*  diag = (float*)(ws + (size_t)4 * 1024 * 1024);        // 64 KB
    float*  sacc = (float*)(ws + (size_t)4 * 1024 * 1024 + 65536);

    norm_kernel<<<N_ROWS / 4, 256, 0, stream>>>(A, P, a8u, p8u, diag, sacc);
    lse_kernel<<<(N_ROWS / BM) * COLSPLIT, 256, 0, stream>>>(a8u, p8u, sacc);
    finalize_kernel<<<1, 1024, 0, stream>>>(sacc, diag, out);
}

// Round 19
// 61.042 us; speedup vs baseline: 1.1925x; 1.1925x over previous
//
#include <hip/hip_runtime.h>
#include <hip/hip_bf16.h>

#define N_ROWS 16384
#define DIM 128

constexpr float INV_T = 1.0f / 0.07f;                 // 14.2857...
constexpr float LOG2E = 1.4426950408889634f;
constexpr float C1    = INV_T * LOG2E;                // 20.6099  (exp2 scale)
constexpr float SOP   = 4.5398160f;                   // sqrt(C1), split per operand
constexpr float LN2   = 0.69314718055994530942f;

typedef int   v4i    __attribute__((ext_vector_type(4)));
typedef int   v8i    __attribute__((ext_vector_type(8)));
typedef float f32x16 __attribute__((ext_vector_type(16)));

typedef const __attribute__((address_space(1))) void* gptr1_t;
typedef __attribute__((address_space(3))) void*       sptr3_t;

// p8 PRE-TILED as the B-operand of mfma_scale_f32_32x32x64_f8f6f4 (proven R14):
// one 32-col tile = 4KB contiguous: [c2][h2][b2][col32][16B]
#define TILE_BYTES 4096
#define BM 128                        /* rows per block (4 waves x 32)    */
#define WROWS 32                      /* rows per wave: HALVED vs R14     */
#define COLSPLIT 16
#define COLS_PER (N_ROWS / COLSPLIT)  /* 1024 */
#define NJT (COLS_PER / 32)           /* 32 tiles */

// ---------------------------------------------------------------------------
// Kernel 1: normalize; both operands scaled by sqrt(C1); fp8 e4m3 outputs
// (A row-major, P tiled); exact fp32 diagonal logit; zeroes sacc. (proven R14)
// ---------------------------------------------------------------------------
__global__ __launch_bounds__(256) void norm_kernel(
    const float* __restrict__ A, const float* __restrict__ P,
    ushort* __restrict__ a8u, ushort* __restrict__ p8u,
    float* __restrict__ diag, float* __restrict__ sacc)
{
    if (threadIdx.x < 4) sacc[blockIdx.x * 4 + threadIdx.x] = 0.f;
    int row  = blockIdx.x * 4 + (threadIdx.x >> 6);
    int lane = threadIdx.x & 63;
    float2 av = *(const float2*)(A + (size_t)row * DIM + lane * 2);
    float2 pv = *(const float2*)(P + (size_t)row * DIM + lane * 2);
    float ssa = av.x * av.x + av.y * av.y;
    float ssp = pv.x * pv.x + pv.y * pv.y;
    float dp  = av.x * pv.x + av.y * pv.y;
    #pragma unroll
    for (int m = 1; m < 64; m <<= 1) {
        ssa += __shfl_xor(ssa, m);
        ssp += __shfl_xor(ssp, m);
        dp  += __shfl_xor(dp,  m);
    }
    float ra = 1.0f / fmaxf(sqrtf(ssa), 1e-12f);
    float rp = 1.0f / fmaxf(sqrtf(ssp), 1e-12f);
    if (lane == 0) diag[row] = dp * ra * rp * INV_T;
    float sa = ra * SOP, sp = rp * SOP;
    int apk = __builtin_amdgcn_cvt_pk_fp8_f32(av.x * sa, av.y * sa, 0, false);
    int ppk = __builtin_amdgcn_cvt_pk_fp8_f32(pv.x * sp, pv.y * sp, 0, false);
    a8u[(size_t)row * 64 + lane] = (ushort)apk;
    size_t off = (size_t)(row >> 5) * 2048 + (lane >> 5) * 1024
               + ((lane >> 4) & 1) * 512 + ((lane >> 3) & 1) * 256
               + (row & 31) * 8 + (lane & 7);
    p8u[off] = (ushort)ppk;
}

// ---------------------------------------------------------------------------
// Kernel 2: per-row sum of exp2(C1*cos - C1) via MX-fp8 32x32x64 MFMA.
// R14 schedule VERBATIM (counted vmcnt, triple-buffered 4KB tiles via
// global_load_lds, one s_barrier/tile, setprio) with HALVED per-wave work:
// 32 rows/wave (was 64), single chained acc (2 MFMA/tile), per-tile acc
// init (no persistent cinit). Register demand ~70 -> ~7 waves/SIMD
// residency cap; grid 2048 supplies 8 blocks/CU. Tests the last untested
// variable: contexts/SIMD at constant total work (all prior configs <=4).
// REG-CAP DISCIPLINE: (256,2) ONLY — tighter caps spill (R2/R4/R6).
// ---------------------------------------------------------------------------
__global__ __launch_bounds__(256, 2) void lse_kernel(
    const ushort* __restrict__ a8u, const ushort* __restrict__ p8u,
    float* __restrict__ s_accum)
{
    __shared__ __attribute__((aligned(16))) char btile[3][TILE_BYTES];

    int colseg = blockIdx.x & (COLSPLIT - 1);   // bid%8 -> XCD-pinned segment
    int rowblk = blockIdx.x / COLSPLIT;         // 0..127
    int wave = threadIdx.x >> 6;
    int lane = threadIdx.x & 63;
    int c31  = lane & 31, hi = lane >> 5;
    int row0 = rowblk * BM + wave * WROWS;

    // A fragments: ONE row-tile x 2 K-chunks, 32B/lane (v8i), row-major a8
    const char* a8 = (const char*)a8u;
    v8i afA0 = *(const v8i*)(a8 + (size_t)(row0 + c31) * 128 +      hi * 32);
    v8i afA1 = *(const v8i*)(a8 + (size_t)(row0 + c31) * 128 + 64 + hi * 32);

    float s0[16];
    #pragma unroll
    for (int r = 0; r < 16; ++r) s0[r] = 0.f;

    const char* seg = (const char*)p8u + (size_t)colseg * NJT * TILE_BYTES;
    char* lds = (char*)&btile[0][0];
    int choff = wave * 1024 + lane * 16;   // each wave stages 1KB of the 4KB tile

    auto STAGE = [&](int t, int buf) {
        __builtin_amdgcn_global_load_lds(
            (gptr1_t)(seg + (size_t)t * TILE_BYTES + choff),
            (sptr3_t)(lds + buf * TILE_BYTES + choff), 16, 0, 0);
    };

    int rdoff = hi * 1024 + c31 * 16;

    // prologue: stage tiles 0,1 -> bufs 0,1 (one load each)
    STAGE(0, 0);
    STAGE(1, 1);

    for (int jt = 0; jt < NJT; ++jt) {
        if (jt < NJT - 1) asm volatile("s_waitcnt vmcnt(1)" ::: "memory");
        else              asm volatile("s_waitcnt vmcnt(0)" ::: "memory");
        __builtin_amdgcn_s_barrier();
        __builtin_amdgcn_sched_barrier(0);

        if (jt + 2 < NJT) STAGE(jt + 2, (jt + 2) % 3);

        const char* tb = lds + (jt % 3) * TILE_BYTES;
        v4i x0 = *(const v4i*)(tb + rdoff);
        v4i y0 = *(const v4i*)(tb + rdoff + 512);
        v4i x1 = *(const v4i*)(tb + 2048 + rdoff);
        v4i y1 = *(const v4i*)(tb + 2048 + rdoff + 512);
        v8i b0, b1;
        #pragma unroll
        for (int j = 0; j < 4; ++j) {
            b0[j] = x0[j]; b0[4 + j] = y0[j];
            b1[j] = x1[j]; b1[4 + j] = y1[j];
        }

        f32x16 acc;
        #pragma unroll
        for (int r = 0; r < 16; ++r) acc[r] = -C1;

        __builtin_amdgcn_s_setprio(1);
        acc = __builtin_amdgcn_mfma_scale_f32_32x32x64_f8f6f4(
            afA0, b0, acc, 0, 0, 0, 0x7f7f7f7f, 0, 0x7f7f7f7f);
        acc = __builtin_amdgcn_mfma_scale_f32_32x32x64_f8f6f4(
            afA1, b1, acc, 0, 0, 0, 0x7f7f7f7f, 0, 0x7f7f7f7f);
        __builtin_amdgcn_s_setprio(0);

        #pragma unroll
        for (int r = 0; r < 16; ++r)
            s0[r] += __builtin_amdgcn_exp2f(acc[r]);
    }

    // reduce each row's 32 column-lanes (within each 32-lane half), one atomic
    #pragma unroll
    for (int r = 0; r < 16; ++r) {
        float v = s0[r];
        v += __shfl_xor(v, 1);
        v += __shfl_xor(v, 2);
        v += __shfl_xor(v, 4);
        v += __shfl_xor(v, 8);
        v += __shfl_xor(v, 16);
        if (c31 == 0)
            atomicAdd(&s_accum[row0 + (r & 3) + 8 * (r >> 2) + 4 * hi], v);
    }
}

// ---------------------------------------------------------------------------
// Kernel 3: loss = mean( ln(s_i) + 1/T - diag_i )
// ---------------------------------------------------------------------------
__global__ __launch_bounds__(1024) void finalize_kernel(
    const float* __restrict__ s_acc, const float* __restrict__ diag,
    float* __restrict__ out)
{
    float acc = 0.f;
    int t = threadIdx.x;
    #pragma unroll
    for (int i = 0; i < 4; ++i) {
        int idx = (i * 1024 + t) * 4;
        float4 sv = *(const float4*)(s_acc + idx);
        float4 dv = *(const float4*)(diag + idx);
        acc += __builtin_amdgcn_logf(sv.x) * LN2 + INV_T - dv.x;
        acc += __builtin_amdgcn_logf(sv.y) * LN2 + INV_T - dv.y;
        acc += __builtin_amdgcn_logf(sv.z) * LN2 + INV_T - dv.z;
        acc += __builtin_amdgcn_logf(sv.w) * LN2 + INV_T - dv.w;
    }
    #pragma unroll
    for (int m = 1; m < 64; m <<= 1) acc += __shfl_xor(acc, m);
    __shared__ float wsum[16];
    if ((t & 63) == 0) wsum[t >> 6] = acc;
    __syncthreads();
    if (t == 0) {
        float r = 0.f;
        #pragma unroll
        for (int i = 0; i < 16; ++i) r += wsum[i];
        out[0] = r / (float)N_ROWS;
    }
}

// ---------------------------------------------------------------------------
extern "C" void kernel_launch(void* const* d_in, const int* in_sizes, int n_in,
                              void* d_out, int out_size, void* d_ws, size_t ws_size,
                              hipStream_t stream)
{
    const float* A = (const float*)d_in[0];
    const float* P = (const float*)d_in[1];
    float* out = (float*)d_out;

    char* ws = (char*)d_ws;
    ushort* a8u  = (ushort*)ws;                                   // 2 MB fp8
    ushort* p8u  = (ushort*)(ws + (size_t)2 * 1024 * 1024);       // 2 MB fp8 tiled
    float*  diag = (float*)(ws + (size_t)4 * 1024 * 1024);        // 64 KB
    float*  sacc = (float*)(ws + (size_t)4 * 1024 * 1024 + 65536);

    norm_kernel<<<N_ROWS / 4, 256, 0, stream>>>(A, P, a8u, p8u, diag, sacc);
    lse_kernel<<<(N_ROWS / BM) * COLSPLIT, 256, 0, stream>>>(a8u, p8u, sacc);
    finalize_kernel<<<1, 1024, 0, stream>>>(sacc, diag, out);
}